// Round 1
// baseline (75.715 us; speedup 1.0000x reference)
//
#include <hip/hip_runtime.h>

#define EPS 1e-7f
#define LOG2E 1.44269504088896340736f

constexpr int BLOCK = 1024;        // 16 waves/block, 1 block/CU @ grid 256
constexpr int JR    = 4;           // j's per thread (register tile)
constexpr int JJ    = 8;           // lane-fast j slots
constexpr int JB    = JJ * JR;     // 32 outputs per block
constexpr int SS    = BLOCK / JJ;  // 128 i-segments per block
constexpr int CHUNK = 1024;        // points staged per LDS chunk
constexpr int PTS   = CHUNK / SS;  // 8 points per thread per chunk

// Block b owns j in [b*JB, b*JB+JB). Thread = (jj, ss), lane-fast jj so each
// 8-lane group broadcasts one LDS address; the 8 distinct ss addresses per wave
// are spread across all 32 banks by the +1-float4 row pad (bank = 4(ss+l)%32).
// Each thread holds JR=4 j's worth of coefficients -> one ds_read_b128 feeds
// 4 pairs (LDS bytes/pair /4) and provides 4 independent t->exp->acc chains.
// Next chunk is prefetched into registers during compute; the syncthreads
// vmcnt(0) drain finds the loads already landed (issued a full phase earlier).
__global__ __launch_bounds__(BLOCK, 4) void nw_block(
    const float2* __restrict__ x,        // M x 2 query points
    const float2* __restrict__ inputs,   // N x 2 data points
    const float*  __restrict__ outputs,  // N
    const float*  __restrict__ bw,       // M
    float*        __restrict__ out,      // M
    int N, int M)
{
    __shared__ float4 pts[SS][PTS + 1];  // +1 float4 row pad: conflict-free reads
    __shared__ float2 red[SS][JB];       // per-(segment, j-slot) partials

    const int tid = threadIdx.x;
    const int jj  = tid & (JJ - 1);
    const int ss  = tid >> 3;            // tid / JJ

    // per-thread coefficients for JR j's: t = c0*s + c1*px + c2*py + c3 (k<0 folded)
    float c0[JR], c1[JR], c2[JR], c3[JR];
    #pragma unroll
    for (int r = 0; r < JR; ++r) {
        const int j = blockIdx.x * JB + jj + r * JJ;
        if (j < M) {
            float2 xj = x[j];
            float  b  = bw[j];
            float  k  = -LOG2E / (2.0f * b * b);       // < 0
            c0[r] = k;
            c1[r] = -2.0f * k * xj.x;
            c2[r] = -2.0f * k * xj.y;
            c3[r] = k * fmaf(xj.x, xj.x, xj.y * xj.y);
        } else {
            c0[r] = c1[r] = c2[r] = c3[r] = 0.f;
        }
    }

    float num[JR], den[JR];
    #pragma unroll
    for (int r = 0; r < JR; ++r) { num[r] = 0.f; den[r] = 0.f; }

    // prefetch chunk 0 into registers
    float2 pr = make_float2(0.f, 0.f);
    float  po = 0.f;
    if (tid < min(CHUNK, N)) { pr = inputs[tid]; po = outputs[tid]; }

    for (int base = 0; base < N; base += CHUNK) {
        const int cnt = min(CHUNK, N - base);
        // stage chunk from registers: point (base+tid) -> pts[tid/8][tid%8]
        if (tid < cnt) {
            pts[tid >> 3][tid & (PTS - 1)] =
                make_float4(pr.x, pr.y, fmaf(pr.x, pr.x, pr.y * pr.y), po);
        } else {
            pts[tid >> 3][tid & (PTS - 1)] =
                make_float4(0.f, 0.f, 3.0e38f, 0.f);   // c0*s -> -inf -> w = 0
        }
        __syncthreads();

        // issue next chunk's global loads; they fly under the compute below
        const int nb = base + CHUNK;
        if (nb < N) {
            const int ncnt = min(CHUNK, N - nb);
            if (tid < ncnt) { pr = inputs[nb + tid]; po = outputs[nb + tid]; }
        }

        // each thread: its segment's PTS contiguous points x JR j's
        const float4* my = pts[ss];
        #pragma unroll
        for (int l = 0; l < PTS; ++l) {
            float4 p = my[l];                           // ds_read_b128, no conflicts
            #pragma unroll
            for (int r = 0; r < JR; ++r) {
                float t = fmaf(c0[r], p.z, fmaf(c1[r], p.x, fmaf(c2[r], p.y, c3[r])));
                float w = __builtin_amdgcn_exp2f(t);
                num[r] = fmaf(w, p.w, num[r]);
                den[r] += w;
            }
        }
        __syncthreads();
    }

    // block-local cross-segment reduction
    #pragma unroll
    for (int r = 0; r < JR; ++r)
        red[ss][jj + r * JJ] = make_float2(num[r], den[r]);
    __syncthreads();
    if (tid < JB) {                                     // slot == tid
        float n = 0.f, d = 0.f;
        for (int s = 0; s < SS; ++s) {
            n += red[s][tid].x;
            d += red[s][tid].y;
        }
        const int jo = blockIdx.x * JB + tid;
        if (jo < M) out[jo] = n / (d + EPS);
    }
}

extern "C" void kernel_launch(void* const* d_in, const int* in_sizes, int n_in,
                              void* d_out, int out_size, void* d_ws, size_t ws_size,
                              hipStream_t stream) {
    // setup_inputs() dict order: x (M*2), inputs (N*2), outputs (N), bandwidth (M)
    const float2* x       = (const float2*)d_in[0];
    const float2* inputs  = (const float2*)d_in[1];
    const float*  outputs = (const float*) d_in[2];
    const float*  bwv     = (const float*) d_in[3];
    const int N = in_sizes[2];   // outputs element count
    const int M = in_sizes[3];   // bandwidth element count
    float*        out     = (float*)d_out;

    dim3 grid((M + JB - 1) / JB);    // 256 blocks @ M=8192
    nw_block<<<grid, BLOCK, 0, stream>>>(x, inputs, outputs, bwv, out, N, M);
}

// Round 3
// 74.122 us; speedup vs baseline: 1.0215x; 1.0215x over previous
//
#include <hip/hip_runtime.h>

#define EPS 1e-7f
#define LOG2E 1.44269504088896340736f

typedef float f32x2 __attribute__((ext_vector_type(2)));

constexpr int BLOCK = 512;         // 8 waves/block
constexpr int JJ    = 8;           // lane-fast j slots
constexpr int JR    = 2;           // j's per thread
constexpr int JB    = JJ * JR;     // 16 outputs per block
constexpr int SS    = BLOCK / JJ;  // 64 i-segments per block
constexpr int CHUNK = 1024;        // points per LDS chunk
constexpr int PTS   = CHUNK / SS;  // 16 points per segment
constexpr int ROW   = PTS + 2;     // 18-float row stride: conflict-free b64 reads

// Grid = M/JB = 512 blocks -> 2 independent blocks/CU (barrier overlap).
// LDS is SoA (x,y,s,o); point-PAIRS load as aligned f32x2 via ds_read_b64.
// Inner math is f32x2 ext-vector __builtin_elementwise_fma: the backend
// selects v_pk_fma_f32 (packed-fp32, correct op_sel by construction) or
// falls back to 2x v_fma_f32 -- correct either way. NO hand asm (R2 failed
// on VOP3P op_sel_hi semantics).
__global__ __launch_bounds__(BLOCK, 4) void nw_block(
    const float2* __restrict__ x,        // M x 2 query points
    const float2* __restrict__ inputs,   // N x 2 data points
    const float*  __restrict__ outputs,  // N
    const float*  __restrict__ bw,       // M
    float*        __restrict__ out,      // M
    int N, int M)
{
    __shared__ __align__(16) float sX[SS][ROW];
    __shared__ __align__(16) float sY[SS][ROW];
    __shared__ __align__(16) float sS[SS][ROW];
    __shared__ __align__(16) float sO[SS][ROW];
    __shared__ float2 red[SS][JB];

    const int tid = threadIdx.x;
    const int jj  = tid & (JJ - 1);
    const int ss  = tid >> 3;

    // per-thread coefficient PAIRS (splat): t = c0*s + c1*px + c2*py + c3, k<0 folded
    f32x2 c0p[JR], c1p[JR], c2p[JR], c3p[JR];
    #pragma unroll
    for (int r = 0; r < JR; ++r) {
        const int j = blockIdx.x * JB + jj + r * JJ;
        float k = 0.f, v1 = 0.f, v2 = 0.f, v3 = 0.f;
        if (j < M) {
            float2 xj = x[j];
            float  b  = bw[j];
            k  = -LOG2E / (2.0f * b * b);              // < 0
            v1 = -2.0f * k * xj.x;
            v2 = -2.0f * k * xj.y;
            v3 = k * fmaf(xj.x, xj.x, xj.y * xj.y);
        }
        c0p[r] = {k, k}; c1p[r] = {v1, v1}; c2p[r] = {v2, v2}; c3p[r] = {v3, v3};
    }

    f32x2 nump[JR], denp[JR];
    #pragma unroll
    for (int r = 0; r < JR; ++r) { nump[r] = {0.f, 0.f}; denp[r] = {0.f, 0.f}; }

    // register prefetch of chunk 0: thread t owns points (2t, 2t+1)
    const float4* in4  = (const float4*)inputs;   // 2 points per float4
    const float2* out2 = (const float2*)outputs;
    float4 pin  = make_float4(0.f, 0.f, 0.f, 0.f);
    float2 pout = make_float2(0.f, 0.f);
    if (2 * tid + 1 < N) { pin = in4[tid]; pout = out2[tid]; }

    for (int base = 0; base < N; base += CHUNK) {
        const int cnt = min(CHUNK, N - base);
        // stage pair (2t, 2t+1) -> row t>>3, slots (2t&15, +1) as b64 SoA writes
        {
            const int  r0 = tid >> 3;
            const int  s0 = (2 * tid) & (PTS - 1);
            const bool v0 = (2 * tid) < cnt;
            const bool v1 = (2 * tid + 1) < cnt;
            f32x2 xp = {v0 ? pin.x : 0.f, v1 ? pin.z : 0.f};
            f32x2 yp = {v0 ? pin.y : 0.f, v1 ? pin.w : 0.f};
            f32x2 sp = {v0 ? fmaf(pin.x, pin.x, pin.y * pin.y) : 3.0e38f,   // pad: c0*s -> -inf -> w=0
                        v1 ? fmaf(pin.z, pin.z, pin.w * pin.w) : 3.0e38f};
            f32x2 op = {v0 ? pout.x : 0.f, v1 ? pout.y : 0.f};
            *(f32x2*)&sX[r0][s0] = xp;
            *(f32x2*)&sY[r0][s0] = yp;
            *(f32x2*)&sS[r0][s0] = sp;
            *(f32x2*)&sO[r0][s0] = op;
        }
        __syncthreads();

        // issue next chunk's global loads; they fly under the compute below
        const int nb = base + CHUNK;
        if (nb < N) {
            const int i0 = (nb >> 1) + tid;
            if (2 * i0 + 1 < N) { pin = in4[i0]; pout = out2[i0]; }
        }

        // compute: this segment's PTS points as PTS/2 pairs x JR j's
        const float* mx = sX[ss];
        const float* my = sY[ss];
        const float* ms = sS[ss];
        const float* mo = sO[ss];
        #pragma unroll
        for (int m = 0; m < PTS / 2; ++m) {
            f32x2 xp = *(const f32x2*)&mx[2 * m];     // ds_read_b64, conflict-free
            f32x2 yp = *(const f32x2*)&my[2 * m];
            f32x2 sp = *(const f32x2*)&ms[2 * m];
            f32x2 op = *(const f32x2*)&mo[2 * m];
            #pragma unroll
            for (int r = 0; r < JR; ++r) {
                f32x2 t = __builtin_elementwise_fma(c2p[r], yp, c3p[r]);
                t = __builtin_elementwise_fma(c1p[r], xp, t);
                t = __builtin_elementwise_fma(c0p[r], sp, t);
                f32x2 w;
                w.x = __builtin_amdgcn_exp2f(t.x);
                w.y = __builtin_amdgcn_exp2f(t.y);
                nump[r] = __builtin_elementwise_fma(w, op, nump[r]);
                denp[r] += w;
            }
        }
        __syncthreads();
    }

    // block-local cross-segment reduction
    #pragma unroll
    for (int r = 0; r < JR; ++r)
        red[ss][jj + r * JJ] = make_float2(nump[r].x + nump[r].y,
                                           denp[r].x + denp[r].y);
    __syncthreads();
    if (tid < JB) {
        float n = 0.f, d = 0.f;
        for (int s = 0; s < SS; ++s) {
            n += red[s][tid].x;
            d += red[s][tid].y;
        }
        const int jo = blockIdx.x * JB + tid;
        if (jo < M) out[jo] = n / (d + EPS);
    }
}

extern "C" void kernel_launch(void* const* d_in, const int* in_sizes, int n_in,
                              void* d_out, int out_size, void* d_ws, size_t ws_size,
                              hipStream_t stream) {
    // setup_inputs() dict order: x (M*2), inputs (N*2), outputs (N), bandwidth (M)
    const float2* x       = (const float2*)d_in[0];
    const float2* inputs  = (const float2*)d_in[1];
    const float*  outputs = (const float*) d_in[2];
    const float*  bwv     = (const float*) d_in[3];
    const int N = in_sizes[2];   // outputs element count
    const int M = in_sizes[3];   // bandwidth element count
    float*        out     = (float*)d_out;

    dim3 grid((M + JB - 1) / JB);    // 512 blocks @ M=8192 -> 2 blocks/CU
    nw_block<<<grid, BLOCK, 0, stream>>>(x, inputs, outputs, bwv, out, N, M);
}